// Round 2
// baseline (3887.325 us; speedup 1.0000x reference)
//
#include <hip/hip_runtime.h>
#include <cstdint>
#include <cstddef>

// Problem constants
#define HD 512      // hidden
#define BB 64       // batch
#define TT 64       // timesteps
#define VV 50257    // vocab
#define GG 2048     // 4*H
#define NBLK 64     // grid: 2 branches * 32 j-blocks (<=256 CUs -> all co-resident)
#define NTHR 256    // 4 waves; wave = one 16-row b-tile

typedef __attribute__((ext_vector_type(8))) short bf16x8;   // 8 bf16 (4 VGPR)
typedef __attribute__((ext_vector_type(4))) float f32x4;

__device__ __forceinline__ float bf2f(unsigned short u) {
  union { unsigned int i; float f; } v; v.i = ((unsigned int)u) << 16; return v.f;
}
__device__ __forceinline__ unsigned short f2bf(float f) {
  union { float f; unsigned int i; } v; v.f = f;
  unsigned int r = (v.i + 0x7fffu + ((v.i >> 16) & 1u)) >> 16;   // RNE
  return (unsigned short)r;
}
__device__ __forceinline__ float sigf(float x) { return 1.0f / (1.0f + __expf(-x)); }

// ---------------- detect: float dtype (fp32 vs bf16) and index width ----------------
__global__ void lstm_detect(const unsigned int* whh, const unsigned int* xq, int* flags) {
  __shared__ int csmall, oddnz;
  if (threadIdx.x == 0) { csmall = 0; oddnz = 0; }
  __syncthreads();
  {
    unsigned int w = whh[threadIdx.x];
    union { unsigned int i; float f; } lo; lo.i = w << 16;
    float a = fabsf(lo.f);
    if (a <= 0.0444f) atomicAdd(&csmall, 1);
  }
  if (threadIdx.x < 64) {
    if (xq[2 * threadIdx.x + 1] != 0) atomicAdd(&oddnz, 1);
  }
  __syncthreads();
  if (threadIdx.x == 0) {
    flags[0] = (csmall >= 240) ? 1 : 0;  // 1 => float inputs are bf16
    flags[1] = (oddnz == 0) ? 1 : 0;     // 1 => x is int64
  }
}

// ---------------- prep: bf16 weight copies, bias sums, index copy, state zero ----------------
struct PrepParams {
  const void* src[18];
  const int* flags;
  unsigned int* bar;
  int* xidx;             // [2][B*T]
  float* bsum0;          // [2][2048]
  float* bsum1;          // [2][2048]
  unsigned short* W0;    // [2][2048][512]   bf16 (Whh0)
  unsigned short* W1;    // [2][2048][1024]  bf16 ([Wih1 | Whh1] along K)
  unsigned short* h0;    // [2][2][64][512]  bf16 ping-pong
  unsigned short* h1;    // [2][2][64][512]
};

__global__ void lstm_prep(PrepParams p) {
  const int F = p.flags[0];
  const int X = p.flags[1];
  const size_t NW0 = (size_t)2 * GG * HD;       // 2,097,152
  const size_t NW1 = (size_t)2 * GG * 1024;     // 4,194,304
  const size_t NBS = (size_t)2 * 2 * GG;        // 8192
  const size_t NXI = (size_t)2 * BB * TT;       // 8192
  const size_t NHZ = 262144;                    // h0+h1 ushort count
  const size_t TOT = NW0 + NW1 + NBS + NXI + NHZ + 64;
  for (size_t g = (size_t)blockIdx.x * blockDim.x + threadIdx.x; g < TOT;
       g += (size_t)gridDim.x * blockDim.x) {
    size_t e = g;
    if (e < NW0) {  // Whh0 -> bf16, same [g][k] layout
      size_t br = e / ((size_t)GG * HD), r = e % ((size_t)GG * HD);
      const void* s = p.src[br ? 11 : 3];
      p.W0[e] = F ? ((const unsigned short*)s)[r] : f2bf(((const float*)s)[r]);
      continue;
    }
    e -= NW0;
    if (e < NW1) {  // [Wih1 | Whh1] K-concat -> bf16 [col][1024]
      size_t br = e / ((size_t)GG * 1024), r = e % ((size_t)GG * 1024);
      size_t col = r >> 10, k = r & 1023;
      const void* s = (k < 512) ? p.src[br ? 14 : 6] : p.src[br ? 15 : 7];
      size_t so = col * HD + (k & 511);
      p.W1[e] = F ? ((const unsigned short*)s)[so] : f2bf(((const float*)s)[so]);
      continue;
    }
    e -= NW1;
    if (e < NBS) {  // bias sums (fp32)
      size_t br = e / (2 * GG), r = e % (2 * GG);
      size_t layer = r / GG, gg = r % GG;
      const void* s1 = p.src[(br ? 12 : 4) + (layer ? 4 : 0)];
      const void* s2 = p.src[(br ? 13 : 5) + (layer ? 4 : 0)];
      float v1 = F ? bf2f(((const unsigned short*)s1)[gg]) : ((const float*)s1)[gg];
      float v2 = F ? bf2f(((const unsigned short*)s2)[gg]) : ((const float*)s2)[gg];
      (layer ? p.bsum1 : p.bsum0)[br * GG + gg] = v1 + v2;
      continue;
    }
    e -= NBS;
    if (e < NXI) {  // indices -> int32
      size_t br = e / (BB * TT), r = e % (BB * TT);
      const void* s = p.src[br ? 1 : 0];
      p.xidx[e] = X ? ((const int*)s)[2 * r] : ((const int*)s)[r];
      continue;
    }
    e -= NXI;
    if (e < NHZ) {  // zero hidden-state ping-pong buffers
      const size_t half = 131072;
      if (e < half) p.h0[e] = 0; else p.h1[e - half] = 0;
      continue;
    }
    e -= NHZ;
    p.bar[e] = 0;   // barrier counter reset every call (replay determinism)
  }
}

// ---------------- grid barrier: monotonic counter, agent scope ----------------
__device__ __forceinline__ void gbar(unsigned int* bar, unsigned int target) {
  __syncthreads();
  if (threadIdx.x == 0) {
    __threadfence();  // release: publish this block's h writes
    __hip_atomic_fetch_add(bar, 1u, __ATOMIC_ACQ_REL, __HIP_MEMORY_SCOPE_AGENT);
    while (__hip_atomic_load(bar, __ATOMIC_ACQUIRE, __HIP_MEMORY_SCOPE_AGENT) < target) {
      __builtin_amdgcn_s_sleep(2);
    }
    __threadfence();  // acquire: invalidate stale cached h
  }
  __syncthreads();
}

// ---------------- main kernel (all 64 blocks co-resident by construction) ----------------
struct LstmParams {
  const void* wih0[2];
  const int* xidx;
  const float* bsum0;
  const float* bsum1;
  const unsigned short* W0;
  const unsigned short* W1;
  unsigned short* h0;
  unsigned short* h1;
  unsigned int* bar;
  const int* flags;
  void* out;
};

__launch_bounds__(NTHR, 1)
__global__ void lstm_main(LstmParams p) {
  const int tid  = threadIdx.x;
  const int lane = tid & 63;
  const int wid  = tid >> 6;        // wave = b-tile
  const int l15  = lane & 15;
  const int lk   = lane >> 4;       // k-group / D-row-group
  const int brr  = blockIdx.x >> 5; // 0=q, 1=f
  const int jblk = blockIdx.x & 31;
  const int jcol = jblk * 16 + l15;
  const int F = p.flags[0];

  const unsigned short* W0 = p.W0 + (size_t)brr * GG * HD;
  const unsigned short* W1 = p.W1 + (size_t)brr * GG * 1024;
  unsigned short* h0b = p.h0 + (size_t)brr * 2 * BB * HD;
  unsigned short* h1b = p.h1 + (size_t)brr * 2 * BB * HD;
  const int* xid = p.xidx + brr * BB * TT;
  const void* wih0 = p.wih0[brr];

  float bs0[4], bs1[4];
#pragma unroll
  for (int q = 0; q < 4; ++q) {
    bs0[q] = p.bsum0[brr * GG + q * HD + jcol];
    bs1[q] = p.bsum1[brr * GG + q * HD + jcol];
  }

  int brow[4];
#pragma unroll
  for (int r = 0; r < 4; ++r) brow[r] = wid * 16 + lk * 4 + r;  // D rows this lane owns
  const int arow = wid * 16 + l15;                              // A row this lane loads

  float c0[4] = {0.f, 0.f, 0.f, 0.f}, c1[4] = {0.f, 0.f, 0.f, 0.f};
  float xg_cur[16], xg_nxt[16];

  // initial gather (t = 0)
#pragma unroll
  for (int r = 0; r < 4; ++r) {
    int idx = xid[brow[r] * TT + 0];
#pragma unroll
    for (int q = 0; q < 4; ++q) {
      size_t off = (size_t)(q * HD + jcol) * VV + (size_t)idx;
      xg_cur[r * 4 + q] = F ? bf2f(((const unsigned short*)wih0)[off])
                            : ((const float*)wih0)[off];
    }
  }

  for (int s = 0; s <= TT; ++s) {
    // prefetch gather for next step (consumed after the next barrier)
    {
      int tn = s + 1; if (tn > TT - 1) tn = TT - 1;
#pragma unroll
      for (int r = 0; r < 4; ++r) {
        int idx = xid[brow[r] * TT + tn];
#pragma unroll
        for (int q = 0; q < 4; ++q) {
          size_t off = (size_t)(q * HD + jcol) * VV + (size_t)idx;
          xg_nxt[r * 4 + q] = F ? bf2f(((const unsigned short*)wih0)[off])
                                : ((const float*)wih0)[off];
        }
      }
    }

    const unsigned short* h0r = h0b + (size_t)((s + 1) & 1) * BB * HD; // h0_{s-1}
    f32x4 acc0[4], acc1[4];

    if (s < TT) {  // layer 0, time s: gates = h0_{s-1} @ Whh0^T
#pragma unroll
      for (int q = 0; q < 4; ++q) acc0[q] = (f32x4){0.f, 0.f, 0.f, 0.f};
      for (int kc = 0; kc < 16; ++kc) {
        const int k0 = kc * 32 + lk * 8;
        bf16x8 av = *(const bf16x8*)(h0r + (size_t)arow * HD + k0);
#pragma unroll
        for (int q = 0; q < 4; ++q) {
          bf16x8 bv = *(const bf16x8*)(W0 + (size_t)(q * HD + jcol) * HD + k0);
          acc0[q] = __builtin_amdgcn_mfma_f32_16x16x32_bf16(av, bv, acc0[q], 0, 0, 0);
        }
      }
    }
    if (s >= 1) {  // layer 1, time s-1: gates = [h0_{s-1} | h1_{s-2}] @ [Wih1|Whh1]^T
      const unsigned short* h1p = h1b + (size_t)(s & 1) * BB * HD;     // h1_{s-2}
#pragma unroll
      for (int q = 0; q < 4; ++q) acc1[q] = (f32x4){0.f, 0.f, 0.f, 0.f};
      for (int kc = 0; kc < 32; ++kc) {
        const int k0 = kc * 32 + lk * 8;
        const unsigned short* asrc = (kc < 16)
            ? (h0r + (size_t)arow * HD + k0)
            : (h1p + (size_t)arow * HD + (k0 - 512));
        bf16x8 av = *(const bf16x8*)asrc;
#pragma unroll
        for (int q = 0; q < 4; ++q) {
          bf16x8 bv = *(const bf16x8*)(W1 + (size_t)(q * HD + jcol) * 1024 + k0);
          acc1[q] = __builtin_amdgcn_mfma_f32_16x16x32_bf16(av, bv, acc1[q], 0, 0, 0);
        }
      }
    }

    if (s < TT) {  // layer-0 cell update; gate order i,f,g,o = q 0..3
      unsigned short* h0w = h0b + (size_t)(s & 1) * BB * HD;
#pragma unroll
      for (int r = 0; r < 4; ++r) {
        float gi = sigf(acc0[0][r] + bs0[0] + xg_cur[r * 4 + 0]);
        float gf = sigf(acc0[1][r] + bs0[1] + xg_cur[r * 4 + 1]);
        float gc = tanhf(acc0[2][r] + bs0[2] + xg_cur[r * 4 + 2]);
        float go = sigf(acc0[3][r] + bs0[3] + xg_cur[r * 4 + 3]);
        c0[r] = gf * c0[r] + gi * gc;
        float hv = go * tanhf(c0[r]);
        h0w[(size_t)brow[r] * HD + jcol] = f2bf(hv);
      }
    }
    if (s >= 1) {  // layer-1 cell update + output write
      unsigned short* h1w = h1b + (size_t)((s - 1) & 1) * BB * HD;
      const int tl = s - 1;
#pragma unroll
      for (int r = 0; r < 4; ++r) {
        float gi = sigf(acc1[0][r] + bs1[0]);
        float gf = sigf(acc1[1][r] + bs1[1]);
        float gc = tanhf(acc1[2][r] + bs1[2]);
        float go = sigf(acc1[3][r] + bs1[3]);
        c1[r] = gf * c1[r] + gi * gc;
        float hv = go * tanhf(c1[r]);
        h1w[(size_t)brow[r] * HD + jcol] = f2bf(hv);
        size_t oo = (((size_t)brr * BB + brow[r]) * TT + tl) * HD + jcol;
        if (F) ((unsigned short*)p.out)[oo] = f2bf(hv);
        else   ((float*)p.out)[oo] = hv;
      }
    }

#pragma unroll
    for (int i2 = 0; i2 < 16; ++i2) xg_cur[i2] = xg_nxt[i2];

    if (s < TT) gbar(p.bar, (unsigned int)(s + 1) * NBLK);
  }
}

// ---------------- host ----------------
extern "C" void kernel_launch(void* const* d_in, const int* in_sizes, int n_in,
                              void* d_out, int out_size, void* d_ws, size_t ws_size,
                              hipStream_t stream) {
  if (n_in < 18) return;
  char* ws = (char*)d_ws;
  size_t off = 0;
  auto alloc = [&](size_t bytes) -> void* {
    off = (off + 255) & ~(size_t)255;
    void* r = ws + off;
    off += bytes;
    return r;
  };
  int* flags           = (int*)alloc(256);
  unsigned int* bar    = (unsigned int*)alloc(256);
  int* xidx            = (int*)alloc((size_t)2 * BB * TT * 4);
  float* bsum0         = (float*)alloc((size_t)2 * GG * 4);
  float* bsum1         = (float*)alloc((size_t)2 * GG * 4);
  unsigned short* W0   = (unsigned short*)alloc((size_t)2 * GG * HD * 2);
  unsigned short* W1   = (unsigned short*)alloc((size_t)2 * GG * 1024 * 2);
  unsigned short* h0   = (unsigned short*)alloc((size_t)2 * 2 * BB * HD * 2);
  unsigned short* h1   = (unsigned short*)alloc((size_t)2 * 2 * BB * HD * 2);
  (void)ws_size; (void)in_sizes; (void)out_size;

  lstm_detect<<<dim3(1), dim3(256), 0, stream>>>(
      (const unsigned int*)d_in[3], (const unsigned int*)d_in[0], flags);

  PrepParams pp;
  for (int i = 0; i < 18; ++i) pp.src[i] = d_in[i];
  pp.flags = flags; pp.bar = bar; pp.xidx = xidx;
  pp.bsum0 = bsum0; pp.bsum1 = bsum1;
  pp.W0 = W0; pp.W1 = W1; pp.h0 = h0; pp.h1 = h1;
  lstm_prep<<<dim3(1024), dim3(256), 0, stream>>>(pp);

  LstmParams lp;
  lp.wih0[0] = d_in[2]; lp.wih0[1] = d_in[10];
  lp.xidx = xidx; lp.bsum0 = bsum0; lp.bsum1 = bsum1;
  lp.W0 = W0; lp.W1 = W1; lp.h0 = h0; lp.h1 = h1;
  lp.bar = bar; lp.flags = flags; lp.out = d_out;

  // Plain launch: 64 blocks x 256 thr, __launch_bounds__(256,1) -> all blocks
  // co-resident on a 256-CU chip; grid barrier is deadlock-free by capacity.
  // (hipLaunchCooperativeKernel is NOT graph-capturable -> replay failure in R1.)
  lstm_main<<<dim3(NBLK), dim3(NTHR), 0, stream>>>(lp);
}

// Round 3
// 3879.291 us; speedup vs baseline: 1.0021x; 1.0021x over previous
//
#include <hip/hip_runtime.h>
#include <cstdint>
#include <cstddef>

// Problem constants
#define HD 512      // hidden
#define BB 64       // batch
#define TT 64       // timesteps
#define VV 50257    // vocab
#define GG 2048     // 4*H
#define NBLK 64     // recurrent grid: 2 branches * 32 j-blocks (all co-resident)
#define NTHR 256    // 4 waves; wave = one 16-row b-tile
#define CHUNK 16384 // gather LDS chunk (floats) = 64 KB

typedef __attribute__((ext_vector_type(8))) short bf16x8;   // 8 bf16 (4 VGPR)
typedef __attribute__((ext_vector_type(4))) float f32x4;

__device__ __forceinline__ float bf2f(unsigned short u) {
  union { unsigned int i; float f; } v; v.i = ((unsigned int)u) << 16; return v.f;
}
__device__ __forceinline__ unsigned short f2bf(float f) {
  union { float f; unsigned int i; } v; v.f = f;
  unsigned int r = (v.i + 0x7fffu + ((v.i >> 16) & 1u)) >> 16;   // RNE
  return (unsigned short)r;
}
__device__ __forceinline__ float sigf(float x) { return 1.0f / (1.0f + __expf(-x)); }

// ---------------- detect: float dtype (fp32 vs bf16) and index width ----------------
__global__ void lstm_detect(const unsigned int* whh, const unsigned int* xq, int* flags) {
  __shared__ int csmall, oddnz;
  if (threadIdx.x == 0) { csmall = 0; oddnz = 0; }
  __syncthreads();
  {
    unsigned int w = whh[threadIdx.x];
    union { unsigned int i; float f; } lo; lo.i = w << 16;
    float a = fabsf(lo.f);
    if (a <= 0.0444f) atomicAdd(&csmall, 1);
  }
  if (threadIdx.x < 64) {
    if (xq[2 * threadIdx.x + 1] != 0) atomicAdd(&oddnz, 1);
  }
  __syncthreads();
  if (threadIdx.x == 0) {
    flags[0] = (csmall >= 240) ? 1 : 0;  // 1 => float inputs are bf16
    flags[1] = (oddnz == 0) ? 1 : 0;     // 1 => x is int64
  }
}

// ---------------- prep: bf16 weight copies, bias sums, index copy, state zero ----------------
struct PrepParams {
  const void* src[18];
  const int* flags;
  unsigned int* bar;     // 128 uints (two counters, 256B apart)
  int* xidx;             // [2][B*T]
  float* bsum0;          // [2][2048]
  float* bsum1;          // [2][2048]
  unsigned short* W0;    // [2][2048][512]   bf16 (Whh0)
  unsigned short* W1;    // [2][2048][1024]  bf16 ([Wih1 | Whh1] along K)
  unsigned short* h0;    // [2][2][64][512]  bf16 ping-pong
  unsigned short* h1;    // [2][2][64][512]
};

__global__ void lstm_prep(PrepParams p) {
  const int F = p.flags[0];
  const int X = p.flags[1];
  const size_t NW0 = (size_t)2 * GG * HD;       // 2,097,152
  const size_t NW1 = (size_t)2 * GG * 1024;     // 4,194,304
  const size_t NBS = (size_t)2 * 2 * GG;        // 8192
  const size_t NXI = (size_t)2 * BB * TT;       // 8192
  const size_t NHZ = 262144;                    // h0+h1 ushort count
  const size_t NBZ = 128;                       // barrier words
  const size_t TOT = NW0 + NW1 + NBS + NXI + NHZ + NBZ;
  for (size_t g = (size_t)blockIdx.x * blockDim.x + threadIdx.x; g < TOT;
       g += (size_t)gridDim.x * blockDim.x) {
    size_t e = g;
    if (e < NW0) {  // Whh0 -> bf16, same [g][k] layout
      size_t br = e / ((size_t)GG * HD), r = e % ((size_t)GG * HD);
      const void* s = p.src[br ? 11 : 3];
      p.W0[e] = F ? ((const unsigned short*)s)[r] : f2bf(((const float*)s)[r]);
      continue;
    }
    e -= NW0;
    if (e < NW1) {  // [Wih1 | Whh1] K-concat -> bf16 [col][1024]
      size_t br = e / ((size_t)GG * 1024), r = e % ((size_t)GG * 1024);
      size_t col = r >> 10, k = r & 1023;
      const void* s = (k < 512) ? p.src[br ? 14 : 6] : p.src[br ? 15 : 7];
      size_t so = col * HD + (k & 511);
      p.W1[e] = F ? ((const unsigned short*)s)[so] : f2bf(((const float*)s)[so]);
      continue;
    }
    e -= NW1;
    if (e < NBS) {  // bias sums (fp32)
      size_t br = e / (2 * GG), r = e % (2 * GG);
      size_t layer = r / GG, gg = r % GG;
      const void* s1 = p.src[(br ? 12 : 4) + (layer ? 4 : 0)];
      const void* s2 = p.src[(br ? 13 : 5) + (layer ? 4 : 0)];
      float v1 = F ? bf2f(((const unsigned short*)s1)[gg]) : ((const float*)s1)[gg];
      float v2 = F ? bf2f(((const unsigned short*)s2)[gg]) : ((const float*)s2)[gg];
      (layer ? p.bsum1 : p.bsum0)[br * GG + gg] = v1 + v2;
      continue;
    }
    e -= NBS;
    if (e < NXI) {  // indices -> int32
      size_t br = e / (BB * TT), r = e % (BB * TT);
      const void* s = p.src[br ? 1 : 0];
      p.xidx[e] = X ? ((const int*)s)[2 * r] : ((const int*)s)[r];
      continue;
    }
    e -= NXI;
    if (e < NHZ) {  // zero hidden-state ping-pong buffers
      const size_t half = 131072;
      if (e < half) p.h0[e] = 0; else p.h1[e - half] = 0;
      continue;
    }
    e -= NHZ;
    p.bar[e] = 0;   // barrier counters reset every call (replay determinism)
  }
}

// ---------------- gather pass: x_proj[g][bt] = Wih0[g][ token[bt] ] ----------------
// One block per (branch, gate-row g). Stream the 201 KB row through LDS in 64 KB
// chunks (coalesced float4 reads, scalar head/tail for the 4B-but-not-16B row
// alignment since V=50257), then emit dense coalesced writes for all 4096 (b,t).
struct GatherParams {
  const void* wih0[2];
  const int* xidx;       // [2][4096]
  void* xp;              // [2*2048][4096] f32 or bf16
  const int* flags;
  int xp32;
};

__launch_bounds__(256, 2)
__global__ void lstm_gather(GatherParams gp) {
  __shared__ float lds[CHUNK];
  const int tid = threadIdx.x;
  const int branch = blockIdx.x >> 11;
  const int g = blockIdx.x & 2047;
  const int F = gp.flags[0];
  const int XP = gp.xp32;

  int tok[16];
  const int* xid = gp.xidx + branch * (BB * TT);
#pragma unroll
  for (int i = 0; i < 16; ++i) tok[i] = xid[tid + 256 * i];

  const size_t rowbase = (size_t)g * VV;
  float* xpf = (float*)gp.xp;
  unsigned short* xpb = (unsigned short*)gp.xp;
  const size_t obase = ((size_t)branch * GG + g) * (size_t)(BB * TT);

  for (int c0 = 0; c0 < VV; c0 += CHUNK) {
    const int cs = (VV - c0 < CHUNK) ? (VV - c0) : CHUNK;
    if (F) {  // bf16 weights: scalar ushort loads (rows only 2B-aligned)
      const unsigned short* r = (const unsigned short*)gp.wih0[branch] + rowbase + c0;
      for (int off = tid; off < cs; off += 256) lds[off] = bf2f(r[off]);
    } else {  // fp32 weights: scalar head/tail + float4 body
      const float* r = (const float*)gp.wih0[branch] + rowbase + c0;
      const int m = (int)(((uintptr_t)r >> 2) & 3);
      int lead = (4 - m) & 3; if (lead > cs) lead = cs;
      if (tid < lead) lds[tid] = r[tid];
      const int nv = (cs - lead) >> 2;
      const f32x4* rv = (const f32x4*)(r + lead);
      for (int v = tid; v < nv; v += 256) {
        f32x4 x = rv[v];
        const int d = lead + v * 4;
        lds[d] = x[0]; lds[d + 1] = x[1]; lds[d + 2] = x[2]; lds[d + 3] = x[3];
      }
      for (int off = lead + nv * 4 + tid; off < cs; off += 256) lds[off] = r[off];
    }
    __syncthreads();
#pragma unroll
    for (int i = 0; i < 16; ++i) {
      const unsigned int t0 = (unsigned int)(tok[i] - c0);
      if (t0 < (unsigned int)cs) {
        const size_t dst = obase + (size_t)(tid + 256 * i);
        if (XP) xpf[dst] = lds[t0];
        else    xpb[dst] = f2bf(lds[t0]);
      }
    }
    __syncthreads();
  }
}

// ---------------- grid barrier: monotonic counter, agent scope ----------------
__device__ __forceinline__ void gbar(unsigned int* bar, unsigned int target) {
  __syncthreads();
  if (threadIdx.x == 0) {
    __threadfence();  // release: publish this block's h writes
    __hip_atomic_fetch_add(bar, 1u, __ATOMIC_ACQ_REL, __HIP_MEMORY_SCOPE_AGENT);
    while (__hip_atomic_load(bar, __ATOMIC_ACQUIRE, __HIP_MEMORY_SCOPE_AGENT) < target) {
      __builtin_amdgcn_s_sleep(2);
    }
    __threadfence();  // acquire: invalidate stale cached h
  }
  __syncthreads();
}

// ---------------- main kernel (64 blocks co-resident by construction) ----------------
struct LstmParams {
  const void* xp;        // precomputed x_proj
  const float* bsum0;
  const float* bsum1;
  const unsigned short* W0;
  const unsigned short* W1;
  unsigned short* h0;
  unsigned short* h1;
  unsigned int* bar;     // bar[0] = branch q, bar[64] = branch f
  const int* flags;
  int xp32;
  void* out;
};

__launch_bounds__(NTHR, 1)
__global__ void lstm_main(LstmParams p) {
  const int tid  = threadIdx.x;
  const int lane = tid & 63;
  const int wid  = tid >> 6;        // wave = b-tile
  const int l15  = lane & 15;
  const int lk   = lane >> 4;       // k-group / D-row-group
  const int brr  = blockIdx.x >> 5; // 0=q, 1=f
  const int jblk = blockIdx.x & 31;
  const int jcol = jblk * 16 + l15;
  const int F = p.flags[0];
  const int XP = p.xp32;

  const unsigned short* W0 = p.W0 + (size_t)brr * GG * HD;
  const unsigned short* W1 = p.W1 + (size_t)brr * GG * 1024;
  unsigned short* h0b = p.h0 + (size_t)brr * 2 * BB * HD;
  unsigned short* h1b = p.h1 + (size_t)brr * 2 * BB * HD;
  const float* xpf = (const float*)p.xp;
  const unsigned short* xpb = (const unsigned short*)p.xp;
  unsigned int* bar = p.bar + brr * 64;

  float bs0[4], bs1[4];
#pragma unroll
  for (int q = 0; q < 4; ++q) {
    bs0[q] = p.bsum0[brr * GG + q * HD + jcol];
    bs1[q] = p.bsum1[brr * GG + q * HD + jcol];
  }

  int brow[4];
#pragma unroll
  for (int r = 0; r < 4; ++r) brow[r] = wid * 16 + lk * 4 + r;  // D rows this lane owns
  const int arow = wid * 16 + l15;                              // A row this lane loads

  // x_proj row base for gate row (q*HD + jcol) of this branch
  size_t xrow[4];
#pragma unroll
  for (int q = 0; q < 4; ++q)
    xrow[q] = ((size_t)brr * GG + q * HD + jcol) * (size_t)(BB * TT);

  float c0[4] = {0.f, 0.f, 0.f, 0.f}, c1[4] = {0.f, 0.f, 0.f, 0.f};
  float xg_cur[16], xg_nxt[16];

  // initial x_proj read (t = 0)
#pragma unroll
  for (int r = 0; r < 4; ++r) {
#pragma unroll
    for (int q = 0; q < 4; ++q) {
      size_t off = xrow[q] + (size_t)brow[r] * TT + 0;
      xg_cur[r * 4 + q] = XP ? xpf[off] : bf2f(xpb[off]);
    }
  }

  for (int s = 0; s <= TT; ++s) {
    // prefetch x_proj for next step (consumed after the next barrier)
    {
      int tn = s + 1; if (tn > TT - 1) tn = TT - 1;
#pragma unroll
      for (int r = 0; r < 4; ++r) {
#pragma unroll
        for (int q = 0; q < 4; ++q) {
          size_t off = xrow[q] + (size_t)brow[r] * TT + tn;
          xg_nxt[r * 4 + q] = XP ? xpf[off] : bf2f(xpb[off]);
        }
      }
    }

    const unsigned short* h0r = h0b + (size_t)((s + 1) & 1) * BB * HD; // h0_{s-1}
    f32x4 acc0[4], acc1[4];

    if (s < TT) {  // layer 0, time s: gates = h0_{s-1} @ Whh0^T
#pragma unroll
      for (int q = 0; q < 4; ++q) acc0[q] = (f32x4){0.f, 0.f, 0.f, 0.f};
      for (int kc = 0; kc < 16; ++kc) {
        const int k0 = kc * 32 + lk * 8;
        bf16x8 av = *(const bf16x8*)(h0r + (size_t)arow * HD + k0);
#pragma unroll
        for (int q = 0; q < 4; ++q) {
          bf16x8 bv = *(const bf16x8*)(W0 + (size_t)(q * HD + jcol) * HD + k0);
          acc0[q] = __builtin_amdgcn_mfma_f32_16x16x32_bf16(av, bv, acc0[q], 0, 0, 0);
        }
      }
    }
    if (s >= 1) {  // layer 1, time s-1: gates = [h0_{s-1} | h1_{s-2}] @ [Wih1|Whh1]^T
      const unsigned short* h1p = h1b + (size_t)(s & 1) * BB * HD;     // h1_{s-2}
#pragma unroll
      for (int q = 0; q < 4; ++q) acc1[q] = (f32x4){0.f, 0.f, 0.f, 0.f};
      for (int kc = 0; kc < 32; ++kc) {
        const int k0 = kc * 32 + lk * 8;
        const unsigned short* asrc = (kc < 16)
            ? (h0r + (size_t)arow * HD + k0)
            : (h1p + (size_t)arow * HD + (k0 - 512));
        bf16x8 av = *(const bf16x8*)asrc;
#pragma unroll
        for (int q = 0; q < 4; ++q) {
          bf16x8 bv = *(const bf16x8*)(W1 + (size_t)(q * HD + jcol) * 1024 + k0);
          acc1[q] = __builtin_amdgcn_mfma_f32_16x16x32_bf16(av, bv, acc1[q], 0, 0, 0);
        }
      }
    }

    if (s < TT) {  // layer-0 cell update; gate order i,f,g,o = q 0..3
      unsigned short* h0w = h0b + (size_t)(s & 1) * BB * HD;
#pragma unroll
      for (int r = 0; r < 4; ++r) {
        float gi = sigf(acc0[0][r] + bs0[0] + xg_cur[r * 4 + 0]);
        float gf = sigf(acc0[1][r] + bs0[1] + xg_cur[r * 4 + 1]);
        float gc = tanhf(acc0[2][r] + bs0[2] + xg_cur[r * 4 + 2]);
        float go = sigf(acc0[3][r] + bs0[3] + xg_cur[r * 4 + 3]);
        c0[r] = gf * c0[r] + gi * gc;
        float hv = go * tanhf(c0[r]);
        h0w[(size_t)brow[r] * HD + jcol] = f2bf(hv);
      }
    }
    if (s >= 1) {  // layer-1 cell update + output write
      unsigned short* h1w = h1b + (size_t)((s - 1) & 1) * BB * HD;
      const int tl = s - 1;
#pragma unroll
      for (int r = 0; r < 4; ++r) {
        float gi = sigf(acc1[0][r] + bs1[0]);
        float gf = sigf(acc1[1][r] + bs1[1]);
        float gc = tanhf(acc1[2][r] + bs1[2]);
        float go = sigf(acc1[3][r] + bs1[3]);
        c1[r] = gf * c1[r] + gi * gc;
        float hv = go * tanhf(c1[r]);
        h1w[(size_t)brow[r] * HD + jcol] = f2bf(hv);
        size_t oo = (((size_t)brr * BB + brow[r]) * TT + tl) * HD + jcol;
        if (F) ((unsigned short*)p.out)[oo] = f2bf(hv);
        else   ((float*)p.out)[oo] = hv;
      }
    }

#pragma unroll
    for (int i2 = 0; i2 < 16; ++i2) xg_cur[i2] = xg_nxt[i2];

    if (s < TT) gbar(bar, (unsigned int)(s + 1) * 32u);
  }
}

// ---------------- host ----------------
extern "C" void kernel_launch(void* const* d_in, const int* in_sizes, int n_in,
                              void* d_out, int out_size, void* d_ws, size_t ws_size,
                              hipStream_t stream) {
  if (n_in < 18) return;
  char* ws = (char*)d_ws;
  size_t off = 0;
  auto alloc = [&](size_t bytes) -> void* {
    off = (off + 255) & ~(size_t)255;
    void* r = ws + off;
    off += bytes;
    return r;
  };
  int* flags           = (int*)alloc(256);
  unsigned int* bar    = (unsigned int*)alloc(512);
  int* xidx            = (int*)alloc((size_t)2 * BB * TT * 4);
  float* bsum0         = (float*)alloc((size_t)2 * GG * 4);
  float* bsum1         = (float*)alloc((size_t)2 * GG * 4);
  unsigned short* W0   = (unsigned short*)alloc((size_t)2 * GG * HD * 2);
  unsigned short* W1   = (unsigned short*)alloc((size_t)2 * GG * 1024 * 2);
  unsigned short* h0   = (unsigned short*)alloc((size_t)2 * 2 * BB * HD * 2);
  unsigned short* h1   = (unsigned short*)alloc((size_t)2 * 2 * BB * HD * 2);

  // x_proj: fp32 if workspace allows (preferred for accuracy), else bf16
  const size_t xp_f32_bytes = (size_t)2 * GG * BB * TT * 4;   // 67.1 MB
  const size_t xp_b16_bytes = (size_t)2 * GG * BB * TT * 2;   // 33.6 MB
  int xp32 = (off + 256 + xp_f32_bytes <= ws_size) ? 1 : 0;
  void* xp = alloc(xp32 ? xp_f32_bytes : xp_b16_bytes);
  (void)in_sizes; (void)out_size;

  lstm_detect<<<dim3(1), dim3(256), 0, stream>>>(
      (const unsigned int*)d_in[3], (const unsigned int*)d_in[0], flags);

  PrepParams pp;
  for (int i = 0; i < 18; ++i) pp.src[i] = d_in[i];
  pp.flags = flags; pp.bar = bar; pp.xidx = xidx;
  pp.bsum0 = bsum0; pp.bsum1 = bsum1;
  pp.W0 = W0; pp.W1 = W1; pp.h0 = h0; pp.h1 = h1;
  lstm_prep<<<dim3(1024), dim3(256), 0, stream>>>(pp);

  GatherParams gp;
  gp.wih0[0] = d_in[2]; gp.wih0[1] = d_in[10];
  gp.xidx = xidx; gp.xp = xp; gp.flags = flags; gp.xp32 = xp32;
  lstm_gather<<<dim3(4096), dim3(256), 0, stream>>>(gp);

  LstmParams lp;
  lp.xp = xp; lp.bsum0 = bsum0; lp.bsum1 = bsum1;
  lp.W0 = W0; lp.W1 = W1; lp.h0 = h0; lp.h1 = h1;
  lp.bar = bar; lp.flags = flags; lp.xp32 = xp32; lp.out = d_out;
  lstm_main<<<dim3(NBLK), dim3(NTHR), 0, stream>>>(lp);
}

// Round 5
// 3241.906 us; speedup vs baseline: 1.1991x; 1.1966x over previous
//
#include <hip/hip_runtime.h>
#include <cstdint>
#include <cstddef>

// Problem constants
#define HD 512      // hidden
#define BB 64       // batch
#define TT 64       // timesteps
#define VV 50257    // vocab
#define GG 2048     // 4*H
#define NBLK 64     // recurrent grid: 2 branches * 32 j-blocks (all co-resident)
#define NTHR 256    // 4 waves; wave = one GATE (q-split, register-resident weights)
#define CHUNK 16384 // gather LDS chunk (floats) = 64 KB

typedef __attribute__((ext_vector_type(8))) short bf16x8;   // 8 bf16 (4 VGPR)
typedef __attribute__((ext_vector_type(4))) float f32x4;

__device__ __forceinline__ float bf2f(unsigned short u) {
  union { unsigned int i; float f; } v; v.i = ((unsigned int)u) << 16; return v.f;
}
__device__ __forceinline__ unsigned short f2bf(float f) {
  union { float f; unsigned int i; } v; v.f = f;
  unsigned int r = (v.i + 0x7fffu + ((v.i >> 16) & 1u)) >> 16;   // RNE
  return (unsigned short)r;
}
__device__ __forceinline__ float sigf(float x) { return 1.0f / (1.0f + __expf(-x)); }

// ---------------- detect: float dtype (fp32 vs bf16) and index width ----------------
__global__ void lstm_detect(const unsigned int* whh, const unsigned int* xq, int* flags) {
  __shared__ int csmall, oddnz;
  if (threadIdx.x == 0) { csmall = 0; oddnz = 0; }
  __syncthreads();
  {
    unsigned int w = whh[threadIdx.x];
    union { unsigned int i; float f; } lo; lo.i = w << 16;
    float a = fabsf(lo.f);
    if (a <= 0.0444f) atomicAdd(&csmall, 1);
  }
  if (threadIdx.x < 64) {
    if (xq[2 * threadIdx.x + 1] != 0) atomicAdd(&oddnz, 1);
  }
  __syncthreads();
  if (threadIdx.x == 0) {
    flags[0] = (csmall >= 240) ? 1 : 0;  // 1 => float inputs are bf16
    flags[1] = (oddnz == 0) ? 1 : 0;     // 1 => x is int64
  }
}

// ---------------- prep: bf16 weight copies, bias sums, index copy, state zero ----------------
struct PrepParams {
  const void* src[18];
  const int* flags;
  unsigned int* bar;     // 128 uints (two counters, 256B apart)
  int* xidx;             // [2][B*T]
  float* bsum0;          // [2][2048]
  float* bsum1;          // [2][2048]
  unsigned short* W0;    // [2][2048][512]   bf16 (Whh0)
  unsigned short* W1;    // [2][2048][1024]  bf16 ([Wih1 | Whh1] along K)
  unsigned short* h0;    // [2][2][64][512]  bf16 ping-pong
  unsigned short* h1;    // [2][2][64][512]
};

__global__ void lstm_prep(PrepParams p) {
  const int F = p.flags[0];
  const int X = p.flags[1];
  const size_t NW0 = (size_t)2 * GG * HD;       // 2,097,152
  const size_t NW1 = (size_t)2 * GG * 1024;     // 4,194,304
  const size_t NBS = (size_t)2 * 2 * GG;        // 8192
  const size_t NXI = (size_t)2 * BB * TT;       // 8192
  const size_t NHZ = 262144;                    // h0+h1 ushort count
  const size_t NBZ = 128;                       // barrier words
  const size_t TOT = NW0 + NW1 + NBS + NXI + NHZ + NBZ;
  for (size_t g = (size_t)blockIdx.x * blockDim.x + threadIdx.x; g < TOT;
       g += (size_t)gridDim.x * blockDim.x) {
    size_t e = g;
    if (e < NW0) {  // Whh0 -> bf16, same [g][k] layout
      size_t br = e / ((size_t)GG * HD), r = e % ((size_t)GG * HD);
      const void* s = p.src[br ? 11 : 3];
      p.W0[e] = F ? ((const unsigned short*)s)[r] : f2bf(((const float*)s)[r]);
      continue;
    }
    e -= NW0;
    if (e < NW1) {  // [Wih1 | Whh1] K-concat -> bf16 [col][1024]
      size_t br = e / ((size_t)GG * 1024), r = e % ((size_t)GG * 1024);
      size_t col = r >> 10, k = r & 1023;
      const void* s = (k < 512) ? p.src[br ? 14 : 6] : p.src[br ? 15 : 7];
      size_t so = col * HD + (k & 511);
      p.W1[e] = F ? ((const unsigned short*)s)[so] : f2bf(((const float*)s)[so]);
      continue;
    }
    e -= NW1;
    if (e < NBS) {  // bias sums (fp32)
      size_t br = e / (2 * GG), r = e % (2 * GG);
      size_t layer = r / GG, gg = r % GG;
      const void* s1 = p.src[(br ? 12 : 4) + (layer ? 4 : 0)];
      const void* s2 = p.src[(br ? 13 : 5) + (layer ? 4 : 0)];
      float v1 = F ? bf2f(((const unsigned short*)s1)[gg]) : ((const float*)s1)[gg];
      float v2 = F ? bf2f(((const unsigned short*)s2)[gg]) : ((const float*)s2)[gg];
      (layer ? p.bsum1 : p.bsum0)[br * GG + gg] = v1 + v2;
      continue;
    }
    e -= NBS;
    if (e < NXI) {  // indices -> int32
      size_t br = e / (BB * TT), r = e % (BB * TT);
      const void* s = p.src[br ? 1 : 0];
      p.xidx[e] = X ? ((const int*)s)[2 * r] : ((const int*)s)[r];
      continue;
    }
    e -= NXI;
    if (e < NHZ) {  // zero hidden-state ping-pong buffers
      const size_t half = 131072;
      if (e < half) p.h0[e] = 0; else p.h1[e - half] = 0;
      continue;
    }
    e -= NHZ;
    p.bar[e] = 0;   // barrier counters reset every call (replay determinism)
  }
}

// ---------------- gather pass: x_proj[g][bt] = Wih0[g][ token[bt] ] ----------------
struct GatherParams {
  const void* wih0[2];
  const int* xidx;       // [2][4096]
  void* xp;              // [2*2048][4096] f32 or bf16
  const int* flags;
  int xp32;
};

__launch_bounds__(256, 2)
__global__ void lstm_gather(GatherParams gp) {
  __shared__ float lds[CHUNK];
  const int tid = threadIdx.x;
  const int branch = blockIdx.x >> 11;
  const int g = blockIdx.x & 2047;
  const int F = gp.flags[0];
  const int XP = gp.xp32;

  int tok[16];
  const int* xid = gp.xidx + branch * (BB * TT);
#pragma unroll
  for (int i = 0; i < 16; ++i) tok[i] = xid[tid + 256 * i];

  const size_t rowbase = (size_t)g * VV;
  float* xpf = (float*)gp.xp;
  unsigned short* xpb = (unsigned short*)gp.xp;
  const size_t obase = ((size_t)branch * GG + g) * (size_t)(BB * TT);

  for (int c0 = 0; c0 < VV; c0 += CHUNK) {
    const int cs = (VV - c0 < CHUNK) ? (VV - c0) : CHUNK;
    if (F) {  // bf16 weights: scalar ushort loads (rows only 2B-aligned)
      const unsigned short* r = (const unsigned short*)gp.wih0[branch] + rowbase + c0;
      for (int off = tid; off < cs; off += 256) lds[off] = bf2f(r[off]);
    } else {  // fp32 weights: scalar head/tail + float4 body
      const float* r = (const float*)gp.wih0[branch] + rowbase + c0;
      const int m = (int)(((uintptr_t)r >> 2) & 3);
      int lead = (4 - m) & 3; if (lead > cs) lead = cs;
      if (tid < lead) lds[tid] = r[tid];
      const int nv = (cs - lead) >> 2;
      const f32x4* rv = (const f32x4*)(r + lead);
      for (int v = tid; v < nv; v += 256) {
        f32x4 x = rv[v];
        const int d = lead + v * 4;
        lds[d] = x[0]; lds[d + 1] = x[1]; lds[d + 2] = x[2]; lds[d + 3] = x[3];
      }
      for (int off = lead + nv * 4 + tid; off < cs; off += 256) lds[off] = r[off];
    }
    __syncthreads();
#pragma unroll
    for (int i = 0; i < 16; ++i) {
      const unsigned int t0 = (unsigned int)(tok[i] - c0);
      if (t0 < (unsigned int)cs) {
        const size_t dst = obase + (size_t)(tid + 256 * i);
        if (XP) xpf[dst] = lds[t0];
        else    xpb[dst] = f2bf(lds[t0]);
      }
    }
    __syncthreads();
  }
}

// ---------------- grid barrier: PROVEN R2/R3 version (fenced, agent scope) ----------
// The acquire fence invalidates L1/L2 each step -- acceptable now because the only
// large per-step reuse (weights) lives in REGISTERS, which fences cannot touch.
__device__ __forceinline__ void gbar(unsigned int* bar, unsigned int target) {
  __syncthreads();
  if (threadIdx.x == 0) {
    __threadfence();  // release: publish this block's h writes (wb dirty L2)
    __hip_atomic_fetch_add(bar, 1u, __ATOMIC_ACQ_REL, __HIP_MEMORY_SCOPE_AGENT);
    while (__hip_atomic_load(bar, __ATOMIC_ACQUIRE, __HIP_MEMORY_SCOPE_AGENT) < target) {
      __builtin_amdgcn_s_sleep(2);
    }
    __threadfence();  // acquire: invalidate stale cached h
  }
  __syncthreads();
}

// ---------------- main kernel (64 blocks co-resident by construction) ----------------
// q-split: wave wid owns gate q=wid (i,f,g,o) for ALL 64 batch rows x 16 jcols.
// Weight B-fragments are per-wave disjoint -> register-resident, no duplication:
//   bw0[16] (64 VGPR) + bw1[32] (128 VGPR) per lane.
// Gate recombination (i,f,g,o per cell) goes through a padded LDS exchange.
struct LstmParams {
  const void* xp;        // precomputed x_proj
  const float* bsum0;
  const float* bsum1;
  const unsigned short* W0;
  const unsigned short* W1;
  unsigned short* h0;
  unsigned short* h1;
  unsigned int* bar;     // bar[0] = branch q, bar[64] = branch f
  const int* flags;
  int xp32;
  void* out;
};

__launch_bounds__(NTHR, 1)
__global__ void lstm_main(LstmParams p) {
  // P exchange: [gate q][row 64][col 16] f32, padded 17 for bank spread
  __shared__ float P0[4][64][17];
  __shared__ float P1[4][64][17];

  const int tid  = threadIdx.x;
  const int lane = tid & 63;
  const int wid  = tid >> 6;        // wave = gate q (0..3)
  const int l15  = lane & 15;
  const int lk   = lane >> 4;       // k-group / C-row-group
  const int brr  = blockIdx.x >> 5; // 0=q, 1=f
  const int jblk = blockIdx.x & 31;
  const int jcol = jblk * 16 + l15;
  const int F = p.flags[0];
  const int XP = p.xp32;

  const unsigned short* W0 = p.W0 + (size_t)brr * GG * HD;
  const unsigned short* W1 = p.W1 + (size_t)brr * GG * 1024;
  unsigned short* h0b = p.h0 + (size_t)brr * 2 * BB * HD;
  unsigned short* h1b = p.h1 + (size_t)brr * 2 * BB * HD;
  const float* xpf = (const float*)p.xp;
  const unsigned short* xpb = (const unsigned short*)p.xp;
  unsigned int* bar = p.bar + brr * 64;

  // ---- register-resident weights: this wave's gate (q=wid), cols jcol, all K
  bf16x8 bw0[16], bw1[32];
  {
    const unsigned short* w0r = W0 + (size_t)(wid * HD + jcol) * HD;      // [512]
    const unsigned short* w1r = W1 + (size_t)(wid * HD + jcol) * 1024;    // [1024]
#pragma unroll
    for (int kc = 0; kc < 16; ++kc)
      bw0[kc] = *(const bf16x8*)(w0r + kc * 32 + lk * 8);
#pragma unroll
    for (int kc = 0; kc < 32; ++kc)
      bw1[kc] = *(const bf16x8*)(w1r + kc * 32 + lk * 8);
  }

  // biases for the UPDATE phase (lane owns cells (brow[r], jcol) for all 4 gates)
  float bs0[4], bs1[4];
#pragma unroll
  for (int q = 0; q < 4; ++q) {
    bs0[q] = p.bsum0[brr * GG + q * HD + jcol];
    bs1[q] = p.bsum1[brr * GG + q * HD + jcol];
  }

  int brow[4];
#pragma unroll
  for (int r = 0; r < 4; ++r) brow[r] = wid * 16 + lk * 4 + r;  // update-phase rows

  size_t xrow[4];
#pragma unroll
  for (int q = 0; q < 4; ++q)
    xrow[q] = ((size_t)brr * GG + q * HD + jcol) * (size_t)(BB * TT);

  float c0[4] = {0.f, 0.f, 0.f, 0.f}, c1[4] = {0.f, 0.f, 0.f, 0.f};
  float xg_cur[16], xg_nxt[16];

#pragma unroll
  for (int r = 0; r < 4; ++r)
#pragma unroll
    for (int q = 0; q < 4; ++q) {
      size_t off = xrow[q] + (size_t)brow[r] * TT + 0;
      xg_cur[r * 4 + q] = XP ? xpf[off] : bf2f(xpb[off]);
    }

  for (int s = 0; s <= TT; ++s) {
    const unsigned short* h0r = h0b + (size_t)((s + 1) & 1) * BB * HD; // h0_{s-1}
    const unsigned short* h1p = h1b + (size_t)(s & 1) * BB * HD;       // h1_{s-2}

    // prefetch x_proj for next step (values land in registers; immune to inv)
    {
      int tn = s + 1; if (tn > TT - 1) tn = TT - 1;
#pragma unroll
      for (int r = 0; r < 4; ++r)
#pragma unroll
        for (int q = 0; q < 4; ++q) {
          size_t off = xrow[q] + (size_t)brow[r] * TT + tn;
          xg_nxt[r * 4 + q] = XP ? xpf[off] : bf2f(xpb[off]);
        }
    }

    f32x4 acc0[4], acc1[4];

    if (s < TT) {  // layer 0, time s: P0[q] = h0_{s-1} @ W0[q-slice]^T
#pragma unroll
      for (int bt = 0; bt < 4; ++bt) acc0[bt] = (f32x4){0.f, 0.f, 0.f, 0.f};
#pragma unroll
      for (int kc = 0; kc < 16; ++kc) {
        const int k0 = kc * 32 + lk * 8;
#pragma unroll
        for (int bt = 0; bt < 4; ++bt) {
          bf16x8 av = *(const bf16x8*)(h0r + (size_t)(bt * 16 + l15) * HD + k0);
          acc0[bt] = __builtin_amdgcn_mfma_f32_16x16x32_bf16(av, bw0[kc], acc0[bt], 0, 0, 0);
        }
      }
    }
    if (s >= 1) {  // layer 1, time s-1: P1[q] = [h0_{s-1} | h1_{s-2}] @ W1[q-slice]^T
#pragma unroll
      for (int bt = 0; bt < 4; ++bt) acc1[bt] = (f32x4){0.f, 0.f, 0.f, 0.f};
#pragma unroll
      for (int kc = 0; kc < 32; ++kc) {
        const int k0 = kc * 32 + lk * 8;
#pragma unroll
        for (int bt = 0; bt < 4; ++bt) {
          const unsigned short* asrc = (kc < 16)
              ? (h0r + (size_t)(bt * 16 + l15) * HD + k0)
              : (h1p + (size_t)(bt * 16 + l15) * HD + (k0 - 512));
          bf16x8 av = *(const bf16x8*)asrc;
          acc1[bt] = __builtin_amdgcn_mfma_f32_16x16x32_bf16(av, bw1[kc], acc1[bt], 0, 0, 0);
        }
      }
    }

    // ---- cross-wave gate exchange (C layout: col=lane&15, row=(lane>>4)*4+reg)
    if (s < TT) {
#pragma unroll
      for (int bt = 0; bt < 4; ++bt)
#pragma unroll
        for (int i = 0; i < 4; ++i)
          P0[wid][bt * 16 + lk * 4 + i][l15] = acc0[bt][i];
    }
    if (s >= 1) {
#pragma unroll
      for (int bt = 0; bt < 4; ++bt)
#pragma unroll
        for (int i = 0; i < 4; ++i)
          P1[wid][bt * 16 + lk * 4 + i][l15] = acc1[bt][i];
    }
    __syncthreads();

    if (s < TT) {  // layer-0 cell update (each lane: rows brow[0..3], col jcol)
      unsigned short* h0w = h0b + (size_t)(s & 1) * BB * HD;
#pragma unroll
      for (int r = 0; r < 4; ++r) {
        const int row = brow[r];
        float gi = sigf(P0[0][row][l15] + bs0[0] + xg_cur[r * 4 + 0]);
        float gf = sigf(P0[1][row][l15] + bs0[1] + xg_cur[r * 4 + 1]);
        float gc = tanhf(P0[2][row][l15] + bs0[2] + xg_cur[r * 4 + 2]);
        float go = sigf(P0[3][row][l15] + bs0[3] + xg_cur[r * 4 + 3]);
        c0[r] = gf * c0[r] + gi * gc;
        float hv = go * tanhf(c0[r]);
        h0w[(size_t)row * HD + jcol] = f2bf(hv);
      }
    }
    if (s >= 1) {  // layer-1 cell update + output write
      unsigned short* h1w = h1b + (size_t)((s - 1) & 1) * BB * HD;
      const int tl = s - 1;
#pragma unroll
      for (int r = 0; r < 4; ++r) {
        const int row = brow[r];
        float gi = sigf(P1[0][row][l15] + bs1[0]);
        float gf = sigf(P1[1][row][l15] + bs1[1]);
        float gc = tanhf(P1[2][row][l15] + bs1[2]);
        float go = sigf(P1[3][row][l15] + bs1[3]);
        c1[r] = gf * c1[r] + gi * gc;
        float hv = go * tanhf(c1[r]);
        h1w[(size_t)row * HD + jcol] = f2bf(hv);
        size_t oo = (((size_t)brr * BB + row) * TT + tl) * HD + jcol;
        if (F) ((unsigned short*)p.out)[oo] = f2bf(hv);
        else   ((float*)p.out)[oo] = hv;
      }
    }

#pragma unroll
    for (int i2 = 0; i2 < 16; ++i2) xg_cur[i2] = xg_nxt[i2];

    if (s < TT) gbar(bar, (unsigned int)(s + 1) * 32u);
  }
}

// ---------------- host ----------------
extern "C" void kernel_launch(void* const* d_in, const int* in_sizes, int n_in,
                              void* d_out, int out_size, void* d_ws, size_t ws_size,
                              hipStream_t stream) {
  if (n_in < 18) return;
  char* ws = (char*)d_ws;
  size_t off = 0;
  auto alloc = [&](size_t bytes) -> void* {
    off = (off + 255) & ~(size_t)255;
    void* r = ws + off;
    off += bytes;
    return r;
  };
  int* flags           = (int*)alloc(256);
  unsigned int* bar    = (unsigned int*)alloc(512);
  int* xidx            = (int*)alloc((size_t)2 * BB * TT * 4);
  float* bsum0         = (float*)alloc((size_t)2 * GG * 4);
  float* bsum1         = (float*)alloc((size_t)2 * GG * 4);
  unsigned short* W0   = (unsigned short*)alloc((size_t)2 * GG * HD * 2);
  unsigned short* W1   = (unsigned short*)alloc((size_t)2 * GG * 1024 * 2);
  unsigned short* h0   = (unsigned short*)alloc((size_t)2 * 2 * BB * HD * 2);
  unsigned short* h1   = (unsigned short*)alloc((size_t)2 * 2 * BB * HD * 2);

  // x_proj: fp32 if workspace allows (preferred for accuracy), else bf16
  const size_t xp_f32_bytes = (size_t)2 * GG * BB * TT * 4;   // 67.1 MB
  const size_t xp_b16_bytes = (size_t)2 * GG * BB * TT * 2;   // 33.6 MB
  int xp32 = (off + 256 + xp_f32_bytes <= ws_size) ? 1 : 0;
  void* xp = alloc(xp32 ? xp_f32_bytes : xp_b16_bytes);
  (void)in_sizes; (void)out_size;

  lstm_detect<<<dim3(1), dim3(256), 0, stream>>>(
      (const unsigned int*)d_in[3], (const unsigned int*)d_in[0], flags);

  PrepParams pp;
  for (int i = 0; i < 18; ++i) pp.src[i] = d_in[i];
  pp.flags = flags; pp.bar = bar; pp.xidx = xidx;
  pp.bsum0 = bsum0; pp.bsum1 = bsum1;
  pp.W0 = W0; pp.W1 = W1; pp.h0 = h0; pp.h1 = h1;
  lstm_prep<<<dim3(1024), dim3(256), 0, stream>>>(pp);

  GatherParams gp;
  gp.wih0[0] = d_in[2]; gp.wih0[1] = d_in[10];
  gp.xidx = xidx; gp.xp = xp; gp.flags = flags; gp.xp32 = xp32;
  lstm_gather<<<dim3(4096), dim3(256), 0, stream>>>(gp);

  LstmParams lp;
  lp.xp = xp; lp.bsum0 = bsum0; lp.bsum1 = bsum1;
  lp.W0 = W0; lp.W1 = W1; lp.h0 = h0; lp.h1 = h1;
  lp.bar = bar; lp.flags = flags; lp.xp32 = xp32; lp.out = d_out;
  lstm_main<<<dim3(NBLK), dim3(NTHR), 0, stream>>>(lp);
}

// Round 6
// 2013.184 us; speedup vs baseline: 1.9309x; 1.6103x over previous
//
#include <hip/hip_runtime.h>
#include <cstdint>
#include <cstddef>

// Problem constants
#define HD 512      // hidden
#define BB 64       // batch
#define TT 64       // timesteps
#define VV 50257    // vocab
#define GG 2048     // 4*H
#define NBLK 128    // 2 branches * 2 btiles * 32 jblks (<=256 CUs -> co-resident)
#define NTHR 256    // 4 waves; wave = one GATE (q-split, register-resident weights)
#define CHUNK 16384 // gather LDS chunk (floats) = 64 KB
#define PS 20       // P-exchange row stride (banks: store 16lk+l15, read 8rp+l15 -> 2/bank, free)

typedef __attribute__((ext_vector_type(8))) short bf16x8;   // 8 bf16 (4 VGPR)
typedef __attribute__((ext_vector_type(4))) float f32x4;
typedef __attribute__((ext_vector_type(2))) float f32x2;

__device__ __forceinline__ float bf2f(unsigned short u) {
  union { unsigned int i; float f; } v; v.i = ((unsigned int)u) << 16; return v.f;
}
__device__ __forceinline__ unsigned short f2bf(float f) {
  union { float f; unsigned int i; } v; v.f = f;
  unsigned int r = (v.i + 0x7fffu + ((v.i >> 16) & 1u)) >> 16;   // RNE
  return (unsigned short)r;
}
__device__ __forceinline__ float sigf(float x) { return 1.0f / (1.0f + __expf(-x)); }

// ---------------- detect: float dtype (fp32 vs bf16) and index width ----------------
__global__ void lstm_detect(const unsigned int* whh, const unsigned int* xq, int* flags) {
  __shared__ int csmall, oddnz;
  if (threadIdx.x == 0) { csmall = 0; oddnz = 0; }
  __syncthreads();
  {
    unsigned int w = whh[threadIdx.x];
    union { unsigned int i; float f; } lo; lo.i = w << 16;
    float a = fabsf(lo.f);
    if (a <= 0.0444f) atomicAdd(&csmall, 1);
  }
  if (threadIdx.x < 64) {
    if (xq[2 * threadIdx.x + 1] != 0) atomicAdd(&oddnz, 1);
  }
  __syncthreads();
  if (threadIdx.x == 0) {
    flags[0] = (csmall >= 240) ? 1 : 0;  // 1 => float inputs are bf16
    flags[1] = (oddnz == 0) ? 1 : 0;     // 1 => x is int64
  }
}

// ---------------- prep: bf16 weight copies, bias sums, index copy, state zero ----------------
struct PrepParams {
  const void* src[18];
  const int* flags;
  unsigned int* bar;     // 128 uints (two counters, 256B apart)
  int* xidx;             // [2][B*T]
  float* bsum0;          // [2][2048]
  float* bsum1;          // [2][2048]
  unsigned short* W0;    // [2][2048][512]   bf16 (Whh0)
  unsigned short* W1;    // [2][2048][1024]  bf16 ([Wih1 | Whh1] along K)
  unsigned short* h0;    // [2][2][64][512]  bf16 ping-pong
  unsigned short* h1;    // [2][2][64][512]
};

__global__ void lstm_prep(PrepParams p) {
  const int F = p.flags[0];
  const int X = p.flags[1];
  const size_t NW0 = (size_t)2 * GG * HD;       // 2,097,152
  const size_t NW1 = (size_t)2 * GG * 1024;     // 4,194,304
  const size_t NBS = (size_t)2 * 2 * GG;        // 8192
  const size_t NXI = (size_t)2 * BB * TT;       // 8192
  const size_t NHZ = 262144;                    // h0+h1 ushort count
  const size_t NBZ = 128;                       // barrier words
  const size_t TOT = NW0 + NW1 + NBS + NXI + NHZ + NBZ;
  for (size_t g = (size_t)blockIdx.x * blockDim.x + threadIdx.x; g < TOT;
       g += (size_t)gridDim.x * blockDim.x) {
    size_t e = g;
    if (e < NW0) {  // Whh0 -> bf16, same [g][k] layout
      size_t br = e / ((size_t)GG * HD), r = e % ((size_t)GG * HD);
      const void* s = p.src[br ? 11 : 3];
      p.W0[e] = F ? ((const unsigned short*)s)[r] : f2bf(((const float*)s)[r]);
      continue;
    }
    e -= NW0;
    if (e < NW1) {  // [Wih1 | Whh1] K-concat -> bf16 [col][1024]
      size_t br = e / ((size_t)GG * 1024), r = e % ((size_t)GG * 1024);
      size_t col = r >> 10, k = r & 1023;
      const void* s = (k < 512) ? p.src[br ? 14 : 6] : p.src[br ? 15 : 7];
      size_t so = col * HD + (k & 511);
      p.W1[e] = F ? ((const unsigned short*)s)[so] : f2bf(((const float*)s)[so]);
      continue;
    }
    e -= NW1;
    if (e < NBS) {  // bias sums (fp32)
      size_t br = e / (2 * GG), r = e % (2 * GG);
      size_t layer = r / GG, gg = r % GG;
      const void* s1 = p.src[(br ? 12 : 4) + (layer ? 4 : 0)];
      const void* s2 = p.src[(br ? 13 : 5) + (layer ? 4 : 0)];
      float v1 = F ? bf2f(((const unsigned short*)s1)[gg]) : ((const float*)s1)[gg];
      float v2 = F ? bf2f(((const unsigned short*)s2)[gg]) : ((const float*)s2)[gg];
      (layer ? p.bsum1 : p.bsum0)[br * GG + gg] = v1 + v2;
      continue;
    }
    e -= NBS;
    if (e < NXI) {  // indices -> int32
      size_t br = e / (BB * TT), r = e % (BB * TT);
      const void* s = p.src[br ? 1 : 0];
      p.xidx[e] = X ? ((const int*)s)[2 * r] : ((const int*)s)[r];
      continue;
    }
    e -= NXI;
    if (e < NHZ) {  // zero hidden-state ping-pong buffers
      const size_t half = 131072;
      if (e < half) p.h0[e] = 0; else p.h1[e - half] = 0;
      continue;
    }
    e -= NHZ;
    p.bar[e] = 0;   // barrier counters reset every call (replay determinism)
  }
}

// ---------------- gather: x_proj[branch][t][g][b] = Wih0[g][ token[b,t] ] ----------
// One block per (branch, gate-row g). Stream the row through LDS; each thread owns
// (t = tid&63, b = (tid>>6)*16 + i, i=0..15) -> 16 consecutive b => 64B dense store.
struct GatherParams {
  const void* wih0[2];
  const int* xidx;       // [2][4096], b-major [b][t]
  void* xp;              // [branch][t][g][b] f32 or bf16
  const int* flags;
  int xp32;
};

__launch_bounds__(256, 2)
__global__ void lstm_gather(GatherParams gp) {
  __shared__ float lds[CHUNK];
  const int tid = threadIdx.x;
  const int branch = blockIdx.x >> 11;
  const int g = blockIdx.x & 2047;
  const int F = gp.flags[0];
  const int XP = gp.xp32;
  const int t  = tid & 63;
  const int bq = tid >> 6;         // 0..3

  int tok[16];
  const int* xid = gp.xidx + branch * (BB * TT);
#pragma unroll
  for (int i = 0; i < 16; ++i) tok[i] = xid[(bq * 16 + i) * TT + t];

  const size_t rowbase = (size_t)g * VV;
  float val[16];
#pragma unroll
  for (int i = 0; i < 16; ++i) val[i] = 0.f;

  for (int c0 = 0; c0 < VV; c0 += CHUNK) {
    const int cs = (VV - c0 < CHUNK) ? (VV - c0) : CHUNK;
    if (F) {  // bf16 weights: scalar ushort loads (rows only 2B-aligned)
      const unsigned short* r = (const unsigned short*)gp.wih0[branch] + rowbase + c0;
      for (int off = tid; off < cs; off += 256) lds[off] = bf2f(r[off]);
    } else {  // fp32 weights: scalar head/tail + float4 body
      const float* r = (const float*)gp.wih0[branch] + rowbase + c0;
      const int m = (int)(((uintptr_t)r >> 2) & 3);
      int lead = (4 - m) & 3; if (lead > cs) lead = cs;
      if (tid < lead) lds[tid] = r[tid];
      const int nv = (cs - lead) >> 2;
      const f32x4* rv = (const f32x4*)(r + lead);
      for (int v = tid; v < nv; v += 256) {
        f32x4 x = rv[v];
        const int d = lead + v * 4;
        lds[d] = x[0]; lds[d + 1] = x[1]; lds[d + 2] = x[2]; lds[d + 3] = x[3];
      }
      for (int off = lead + nv * 4 + tid; off < cs; off += 256) lds[off] = r[off];
    }
    __syncthreads();
#pragma unroll
    for (int i = 0; i < 16; ++i) {
      const unsigned int t0 = (unsigned int)(tok[i] - c0);
      if (t0 < (unsigned int)cs) val[i] = lds[t0];
    }
    __syncthreads();
  }

  // dense write: [branch][t][g][b= bq*16 .. bq*16+15]
  const size_t base = (((size_t)branch * TT + t) * GG + g) * BB + bq * 16;
  if (XP) {
    float* xpf = (float*)gp.xp;
#pragma unroll
    for (int v = 0; v < 4; ++v) {
      f32x4 x = { val[v*4+0], val[v*4+1], val[v*4+2], val[v*4+3] };
      *(f32x4*)(xpf + base + v * 4) = x;
    }
  } else {
    unsigned short* xpb = (unsigned short*)gp.xp;
#pragma unroll
    for (int i = 0; i < 16; ++i) xpb[base + i] = f2bf(val[i]);
  }
}

// ---------------- grid barrier: PROVEN fenced version (agent scope) ----------------
// Acquire fence invalidates L1/L2 each step -- weights live in REGISTERS so the
// only refetch is h + x_proj (now dense + branch-per-XCD-group).
__device__ __forceinline__ void gbar(unsigned int* bar, unsigned int target) {
  __syncthreads();
  if (threadIdx.x == 0) {
    __threadfence();  // release: publish this block's h writes
    __hip_atomic_fetch_add(bar, 1u, __ATOMIC_ACQ_REL, __HIP_MEMORY_SCOPE_AGENT);
    while (__hip_atomic_load(bar, __ATOMIC_ACQUIRE, __HIP_MEMORY_SCOPE_AGENT) < target) {
      __builtin_amdgcn_s_sleep(2);
    }
    __threadfence();  // acquire: invalidate stale cached h
  }
  __syncthreads();
}

// ---------------- main kernel (128 blocks co-resident by construction) --------------
// Block = (branch, btile of 32 rows, jblk of 16 cols); wave = gate q.
// Register-resident weights: bw0[16] + bw1[32] per lane (disjoint per wave).
// XCD swizzle: xcd=bid&7; branch = xcd>=4 -> each XCD caches ONE branch's h/x_proj.
struct LstmParams {
  const void* xp;        // precomputed x_proj [branch][t][g][b]
  const float* bsum0;
  const float* bsum1;
  const unsigned short* W0;
  const unsigned short* W1;
  unsigned short* h0;
  unsigned short* h1;
  unsigned int* bar;     // bar[0] = branch q, bar[64] = branch f
  const int* flags;
  int xp32;
  void* out;
};

__launch_bounds__(NTHR, 1)
__global__ void lstm_main(LstmParams p) {
  // P exchange: [gate q][row_local 32][col 16] f32, row stride PS=20 (bank-free)
  __shared__ float P0[4][32][PS];
  __shared__ float P1[4][32][PS];

  const int tid  = threadIdx.x;
  const int lane = tid & 63;
  const int wid  = tid >> 6;        // wave = gate q (0..3)
  const int l15  = tid & 15;
  const int lk   = (tid & 63) >> 4; // k-group within wave (0..3)
  const int rp   = tid >> 4;        // update-phase row-pair (0..15)

  // XCD-aware decomposition (performance heuristic only; any bijection correct)
  const int bid  = blockIdx.x;
  const int xcd  = bid & 7;
  const int rest = bid >> 3;                 // 0..15
  const int brr  = (xcd >= 4) ? 1 : 0;
  const int u    = (xcd & 3) + rest * 4;     // 0..63
  const int btile = u & 1;
  const int jblk  = u >> 1;                  // 0..31
  const int jcol  = jblk * 16 + l15;
  const int F = p.flags[0];
  const int XP = p.xp32;

  const unsigned short* W0 = p.W0 + (size_t)brr * GG * HD;
  const unsigned short* W1 = p.W1 + (size_t)brr * GG * 1024;
  unsigned short* h0b = p.h0 + (size_t)brr * 2 * BB * HD;
  unsigned short* h1b = p.h1 + (size_t)brr * 2 * BB * HD;
  const float* xpf = (const float*)p.xp;
  const unsigned short* xpb = (const unsigned short*)p.xp;
  unsigned int* bar = p.bar + brr * 64;

  // ---- register-resident weights: this wave's gate (q=wid), cols jcol, all K
  bf16x8 bw0[16], bw1[32];
  {
    const unsigned short* w0r = W0 + (size_t)(wid * HD + jcol) * HD;
    const unsigned short* w1r = W1 + (size_t)(wid * HD + jcol) * 1024;
#pragma unroll
    for (int kc = 0; kc < 16; ++kc)
      bw0[kc] = *(const bf16x8*)(w0r + kc * 32 + lk * 8);
#pragma unroll
    for (int kc = 0; kc < 32; ++kc)
      bw1[kc] = *(const bf16x8*)(w1r + kc * 32 + lk * 8);
  }

  // biases for the UPDATE phase (lane owns rows rp*2+{0,1}, col jcol, all gates)
  float bs0[4], bs1[4];
#pragma unroll
  for (int q = 0; q < 4; ++q) {
    bs0[q] = p.bsum0[brr * GG + q * HD + jcol];
    bs1[q] = p.bsum1[brr * GG + q * HD + jcol];
  }

  // x_proj base for (branch, gate row q*512+jcol): [t][g][b], b = btile*32 + rp*2
  const int bglob0 = btile * 32 + rp * 2;    // first of this thread's 2 batch rows
  size_t xgbase[4];
#pragma unroll
  for (int q = 0; q < 4; ++q)
    xgbase[q] = (((size_t)brr * TT) * GG + (size_t)(q * HD + jcol)) * BB + bglob0;

  float c0[2] = {0.f, 0.f}, c1[2] = {0.f, 0.f};
  float xgc[8], xgn[8];   // [q*2 + r]

#pragma unroll
  for (int q = 0; q < 4; ++q) {
    if (XP) {
      f32x2 v = *(const f32x2*)(xpf + xgbase[q] + (size_t)0 * GG * BB);
      xgc[q * 2 + 0] = v[0]; xgc[q * 2 + 1] = v[1];
    } else {
      xgc[q * 2 + 0] = bf2f(xpb[xgbase[q]]);
      xgc[q * 2 + 1] = bf2f(xpb[xgbase[q] + 1]);
    }
  }

  for (int s = 0; s <= TT; ++s) {
    const unsigned short* h0r = h0b + (size_t)((s + 1) & 1) * BB * HD; // h0_{s-1}
    const unsigned short* h1p = h1b + (size_t)(s & 1) * BB * HD;       // h1_{s-2}

    // prefetch x_proj for next step (dense [t][g][b] plane)
    {
      int tn = s + 1; if (tn > TT - 1) tn = TT - 1;
      const size_t toff = (size_t)tn * GG * BB;
#pragma unroll
      for (int q = 0; q < 4; ++q) {
        if (XP) {
          f32x2 v = *(const f32x2*)(xpf + xgbase[q] + toff);
          xgn[q * 2 + 0] = v[0]; xgn[q * 2 + 1] = v[1];
        } else {
          xgn[q * 2 + 0] = bf2f(xpb[xgbase[q] + toff]);
          xgn[q * 2 + 1] = bf2f(xpb[xgbase[q] + toff + 1]);
        }
      }
    }

    f32x4 acc0[2], acc1[2];

    if (s < TT) {  // layer 0, time s: P0[q] = h0_{s-1}[btile rows] @ W0[q-slice]^T
#pragma unroll
      for (int bt = 0; bt < 2; ++bt) acc0[bt] = (f32x4){0.f, 0.f, 0.f, 0.f};
#pragma unroll
      for (int kc = 0; kc < 16; ++kc) {
        const int k0 = kc * 32 + lk * 8;
#pragma unroll
        for (int bt = 0; bt < 2; ++bt) {
          bf16x8 av = *(const bf16x8*)(h0r + (size_t)(btile * 32 + bt * 16 + l15) * HD + k0);
          acc0[bt] = __builtin_amdgcn_mfma_f32_16x16x32_bf16(av, bw0[kc], acc0[bt], 0, 0, 0);
        }
      }
    }
    if (s >= 1) {  // layer 1, time s-1: P1[q] = [h0_{s-1} | h1_{s-2}] @ W1[q-slice]^T
#pragma unroll
      for (int bt = 0; bt < 2; ++bt) acc1[bt] = (f32x4){0.f, 0.f, 0.f, 0.f};
#pragma unroll
      for (int kc = 0; kc < 32; ++kc) {
        const int k0 = kc * 32 + lk * 8;
#pragma unroll
        for (int bt = 0; bt < 2; ++bt) {
          const size_t row = (size_t)(btile * 32 + bt * 16 + l15);
          const unsigned short* asrc = (kc < 16)
              ? (h0r + row * HD + k0)
              : (h1p + row * HD + (k0 - 512));
          bf16x8 av = *(const bf16x8*)asrc;
          acc1[bt] = __builtin_amdgcn_mfma_f32_16x16x32_bf16(av, bw1[kc], acc1[bt], 0, 0, 0);
        }
      }
    }

    // ---- cross-wave gate exchange (C layout: col=lane&15, row=(lane>>4)*4+reg)
    if (s < TT) {
#pragma unroll
      for (int bt = 0; bt < 2; ++bt)
#pragma unroll
        for (int i = 0; i < 4; ++i)
          P0[wid][bt * 16 + lk * 4 + i][l15] = acc0[bt][i];
    }
    if (s >= 1) {
#pragma unroll
      for (int bt = 0; bt < 2; ++bt)
#pragma unroll
        for (int i = 0; i < 4; ++i)
          P1[wid][bt * 16 + lk * 4 + i][l15] = acc1[bt][i];
    }
    __syncthreads();

    if (s < TT) {  // layer-0 cell update (lane: rows rp*2+{0,1}, col jcol)
      unsigned short* h0w = h0b + (size_t)(s & 1) * BB * HD;
#pragma unroll
      for (int r = 0; r < 2; ++r) {
        const int rl = rp * 2 + r;
        const int rg = btile * 32 + rl;
        float gi = sigf(P0[0][rl][l15] + bs0[0] + xgc[0 * 2 + r]);
        float gf = sigf(P0[1][rl][l15] + bs0[1] + xgc[1 * 2 + r]);
        float gc = tanhf(P0[2][rl][l15] + bs0[2] + xgc[2 * 2 + r]);
        float go = sigf(P0[3][rl][l15] + bs0[3] + xgc[3 * 2 + r]);
        c0[r] = gf * c0[r] + gi * gc;
        float hv = go * tanhf(c0[r]);
        h0w[(size_t)rg * HD + jcol] = f2bf(hv);
      }
    }
    if (s >= 1) {  // layer-1 cell update + output write
      unsigned short* h1w = h1b + (size_t)((s - 1) & 1) * BB * HD;
      const int tl = s - 1;
#pragma unroll
      for (int r = 0; r < 2; ++r) {
        const int rl = rp * 2 + r;
        const int rg = btile * 32 + rl;
        float gi = sigf(P1[0][rl][l15] + bs1[0]);
        float gf = sigf(P1[1][rl][l15] + bs1[1]);
        float gc = tanhf(P1[2][rl][l15] + bs1[2]);
        float go = sigf(P1[3][rl][l15] + bs1[3]);
        c1[r] = gf * c1[r] + gi * gc;
        float hv = go * tanhf(c1[r]);
        h1w[(size_t)rg * HD + jcol] = f2bf(hv);
        size_t oo = (((size_t)brr * BB + rg) * TT + tl) * HD + jcol;
        if (F) ((unsigned short*)p.out)[oo] = f2bf(hv);
        else   ((float*)p.out)[oo] = hv;
      }
    }

#pragma unroll
    for (int i2 = 0; i2 < 8; ++i2) xgc[i2] = xgn[i2];

    if (s < TT) gbar(bar, (unsigned int)(s + 1) * 64u);  // 64 blocks per branch
  }
}

// ---------------- host ----------------
extern "C" void kernel_launch(void* const* d_in, const int* in_sizes, int n_in,
                              void* d_out, int out_size, void* d_ws, size_t ws_size,
                              hipStream_t stream) {
  if (n_in < 18) return;
  char* ws = (char*)d_ws;
  size_t off = 0;
  auto alloc = [&](size_t bytes) -> void* {
    off = (off + 255) & ~(size_t)255;
    void* r = ws + off;
    off += bytes;
    return r;
  };
  int* flags           = (int*)alloc(256);
  unsigned int* bar    = (unsigned int*)alloc(512);
  int* xidx            = (int*)alloc((size_t)2 * BB * TT * 4);
  float* bsum0         = (float*)alloc((size_t)2 * GG * 4);
  float* bsum1         = (float*)alloc((size_t)2 * GG * 4);
  unsigned short* W0   = (unsigned short*)alloc((size_t)2 * GG * HD * 2);
  unsigned short* W1   = (unsigned short*)alloc((size_t)2 * GG * 1024 * 2);
  unsigned short* h0   = (unsigned short*)alloc((size_t)2 * 2 * BB * HD * 2);
  unsigned short* h1   = (unsigned short*)alloc((size_t)2 * 2 * BB * HD * 2);

  // x_proj: fp32 if workspace allows (preferred for accuracy), else bf16
  const size_t xp_f32_bytes = (size_t)2 * TT * GG * BB * 4;   // 67.1 MB
  const size_t xp_b16_bytes = (size_t)2 * TT * GG * BB * 2;   // 33.6 MB
  int xp32 = (off + 256 + xp_f32_bytes <= ws_size) ? 1 : 0;
  void* xp = alloc(xp32 ? xp_f32_bytes : xp_b16_bytes);
  (void)in_sizes; (void)out_size;

  lstm_detect<<<dim3(1), dim3(256), 0, stream>>>(
      (const unsigned int*)d_in[3], (const unsigned int*)d_in[0], flags);

  PrepParams pp;
  for (int i = 0; i < 18; ++i) pp.src[i] = d_in[i];
  pp.flags = flags; pp.bar = bar; pp.xidx = xidx;
  pp.bsum0 = bsum0; pp.bsum1 = bsum1;
  pp.W0 = W0; pp.W1 = W1; pp.h0 = h0; pp.h1 = h1;
  lstm_prep<<<dim3(1024), dim3(256), 0, stream>>>(pp);

  GatherParams gp;
  gp.wih0[0] = d_in[2]; gp.wih0[1] = d_in[10];
  gp.xidx = xidx; gp.xp = xp; gp.flags = flags; gp.xp32 = xp32;
  lstm_gather<<<dim3(4096), dim3(256), 0, stream>>>(gp);

  LstmParams lp;
  lp.xp = xp; lp.bsum0 = bsum0; lp.bsum1 = bsum1;
  lp.W0 = W0; lp.W1 = W1; lp.h0 = h0; lp.h1 = h1;
  lp.bar = bar; lp.flags = flags; lp.xp32 = xp32; lp.out = d_out;
  lstm_main<<<dim3(NBLK), dim3(NTHR), 0, stream>>>(lp);
}